// Round 9
// baseline (968.175 us; speedup 1.0000x reference)
//
#include <hip/hip_runtime.h>
#include <hip/hip_bf16.h>
#include <cstdint>

#define NN 50000
#define NE 800000
#define DH 128
#define TILES 50000   // NE/16

typedef __bf16 bf16;
typedef __bf16 bf16x8 __attribute__((ext_vector_type(8)));
typedef float  f32x4  __attribute__((ext_vector_type(4)));

__device__ __forceinline__ float fast_silu(float x) {
    float e = __expf(-x);
    return x * __builtin_amdgcn_rcpf(1.0f + e);
}

// ---------------- k0: weight prep ----------------
// w1aT/w1bT/w2T: [n][k] transposed bf16 (A/B-frag friendly).
// w3P: W3^T pre-permuted for the chained GEMM2 A-operand:
//   i = ((s2*8+t2)*64 + lane)*8 + j ; g=lane>>4, r=lane&15
//   n_in = (2*s2 + (j>>2))*16 + 4*g + (j&3)   (the k_hw->n permutation)
//   w3P[i] = W3[n_in][t2*16 + r]
// smalls: w1c,b1,g1,bt1,b2 (5*128) ... + (b3,W4) interleaved pairs at 896.
__global__ void prep_kernel(const float* __restrict__ W1, const float* __restrict__ W2,
                            const float* __restrict__ W3, const float* __restrict__ b1,
                            const float* __restrict__ g1, const float* __restrict__ bt1,
                            const float* __restrict__ b2, const float* __restrict__ b3,
                            const float* __restrict__ W4,
                            bf16* __restrict__ w1aT, bf16* __restrict__ w1bT,
                            bf16* __restrict__ w2T,  bf16* __restrict__ w3P,
                            float* __restrict__ smalls) {
    int i = blockIdx.x * 256 + threadIdx.x;   // 0..16383
    int n = i >> 7, k = i & 127;
    w1aT[i] = (bf16)W1[k * DH + n];
    w1bT[i] = (bf16)W1[(k + DH) * DH + n];
    w2T[i]  = (bf16)W2[k * DH + n];
    {
        int j = i & 7, l = (i >> 3) & 63, t2 = (i >> 9) & 7, s2 = (i >> 12) & 3;
        int g = l >> 4, r = l & 15;
        int n_in = (2 * s2 + (j >> 2)) * 16 + 4 * g + (j & 3);
        w3P[i] = (bf16)W3[n_in * DH + t2 * 16 + r];
    }
    if (i < DH) {
        smalls[i]           = W1[256 * DH + i]; // w1c
        smalls[DH + i]      = b1[i];
        smalls[2 * DH + i]  = g1[i];
        smalls[3 * DH + i]  = bt1[i];
        smalls[4 * DH + i]  = b2[i];
        smalls[896 + 2 * i]     = b3[i];
        smalls[896 + 2 * i + 1] = W4[i];
    }
}

// ---------------- k1: A = h@W1a, B = h@W1b (bf16 out) ----------------
__global__ __launch_bounds__(256) void node_kernel(const float* __restrict__ h,
                                                   const bf16* __restrict__ w1aT,
                                                   const bf16* __restrict__ w1bT,
                                                   bf16* __restrict__ An,
                                                   bf16* __restrict__ Bn) {
    int lane = threadIdx.x & 63, wid = threadIdx.x >> 6;
    int r = lane & 15, g = lane >> 4;
    int wt = blockIdx.x * 4 + wid;
    if (wt >= (NN / 16)) return;
    int base = wt * 16;
    int node = base + r;

    bf16x8 ha[4];
#pragma unroll
    for (int s = 0; s < 4; s++) {
        const float* hp = h + (size_t)node * DH + s * 32 + g * 8;
        float4 p0 = *(const float4*)hp;
        float4 p1 = *(const float4*)(hp + 4);
        ha[s][0] = (bf16)p0.x; ha[s][1] = (bf16)p0.y;
        ha[s][2] = (bf16)p0.z; ha[s][3] = (bf16)p0.w;
        ha[s][4] = (bf16)p1.x; ha[s][5] = (bf16)p1.y;
        ha[s][6] = (bf16)p1.z; ha[s][7] = (bf16)p1.w;
    }
#pragma unroll
    for (int t = 0; t < 16; t++) {
        const bf16* wmat = (t < 8) ? w1aT : w1bT;
        int n = (t & 7) * 16 + r;
        f32x4 acc = {0.f, 0.f, 0.f, 0.f};
#pragma unroll
        for (int s = 0; s < 4; s++) {
            bf16x8 wb = *(const bf16x8*)(wmat + n * DH + s * 32 + g * 8);
            acc = __builtin_amdgcn_mfma_f32_16x16x32_bf16(ha[s], wb, acc, 0, 0, 0);
        }
        bf16* dst = (t < 8) ? An : Bn;
#pragma unroll
        for (int jj = 0; jj < 4; jj++)
            dst[(size_t)(base + g * 4 + jj) * DH + (t & 7) * 16 + r] = (bf16)acc[jj];
    }
}

// ---------------- k2: out = x ----------------
__global__ void init_kernel(const float* __restrict__ x, float* __restrict__ out, int n) {
    int i = blockIdx.x * 256 + threadIdx.x;
    if (i < n) out[i] = x[i];
}

// ---------------- k3: fused edge kernel, chained MFMA (no y LDS exchange) ----
// Swapped GEMMs: y^T = mfma(W2frag_A, z^T_B); silu+b2 packed straight into
// GEMM2 B-frags (k-permutation baked into w3P); p^T = mfma(w3Pfrag, pb).
// Lane keeps col=edge throughout. LDS = 4.6KB biases only, no barriers.
__global__ __launch_bounds__(512, 2) void edge_kernel(
    const bf16* __restrict__ An, const bf16* __restrict__ Bn,
    const bf16* __restrict__ w2T, const bf16* __restrict__ w3P,
    const float* __restrict__ smalls, const float* __restrict__ b4p,
    const int* __restrict__ e, const float* __restrict__ dxv,
    const float* __restrict__ d2, float* __restrict__ out) {
    __shared__ float sSm[1152];

    int tid = threadIdx.x;
    if (tid < 128) {
#pragma unroll
        for (int a = 0; a < 9; a++) sSm[a * 128 + tid] = smalls[a * 128 + tid];
    }
    __syncthreads();

    const float* s_w1c = sSm;
    const float* s_b1  = sSm + 128;
    const float* s_g1  = sSm + 256;
    const float* s_bt1 = sSm + 384;
    const float* s_b2  = sSm + 512;
    const float* s_bw  = sSm + 896;   // (b3,W4) pairs
    float b4v = b4p[0];

    int lane = tid & 63, wid = tid >> 6;
    int r = lane & 15, g = lane >> 4;
    const bf16* w2base = w2T + r * DH + g * 8;       // A-frag row=r, k-chunk g
    const bf16* w3base = w3P + (size_t)lane * 8;     // [s2][t2][lane][8]
    int wgid = blockIdx.x * 8 + wid;
    int nw = gridDim.x * 8;

    for (int tile = wgid; tile < TILES; tile += nw) {
        int base = tile * 16;
        int ei = e[base + r];
        int ej = e[NE + base + r];
        float d2v = d2[base + r];
        const bf16* Ar = An + (size_t)ei * DH;
        const bf16* Br = Bn + (size_t)ej * DH;

        // z = silu(A[ei]+B[ej]+d2*w1c+b1): lane r holds edge base+r's features
        float z[4][8];
#pragma unroll
        for (int s = 0; s < 4; s++) {
            bf16x8 av = *(const bf16x8*)(Ar + s * 32 + g * 8);
            bf16x8 bv = *(const bf16x8*)(Br + s * 32 + g * 8);
#pragma unroll
            for (int j = 0; j < 8; j++) {
                int f = s * 32 + g * 8 + j;
                float zz = (float)av[j] + (float)bv[j] + d2v * s_w1c[f] + s_b1[f];
                z[s][j] = fast_silu(zz);
            }
        }
        // LayerNorm over the 4 lanes holding this edge (xor 16, 32)
        float sum = 0.f, sq = 0.f;
#pragma unroll
        for (int s = 0; s < 4; s++)
#pragma unroll
            for (int j = 0; j < 8; j++) { sum += z[s][j]; sq += z[s][j] * z[s][j]; }
        sum += __shfl_xor(sum, 16); sq += __shfl_xor(sq, 16);
        sum += __shfl_xor(sum, 32); sq += __shfl_xor(sq, 32);
        float mu = sum * 0.0078125f;
        float var = sq * 0.0078125f - mu * mu;
        float rs = __builtin_amdgcn_rsqf(var + 1e-5f);

        bf16x8 af[4];                 // z^T B-fragments (col=edge=r)
#pragma unroll
        for (int s = 0; s < 4; s++)
#pragma unroll
            for (int j = 0; j < 8; j++) {
                int f = s * 32 + g * 8 + j;
                af[s][j] = (bf16)((z[s][j] - mu) * rs * s_g1[f] + s_bt1[f]);
            }

        // GEMM1 swapped: y^T[t*16+4g+jj][edge r] in acc1[t][jj]
        f32x4 acc1[8];
#pragma unroll
        for (int t = 0; t < 8; t++) {
            f32x4 acc = {0.f, 0.f, 0.f, 0.f};
#pragma unroll
            for (int s = 0; s < 4; s++) {
                bf16x8 wa = *(const bf16x8*)(w2base + t * 16 * DH + s * 32);
                acc = __builtin_amdgcn_mfma_f32_16x16x32_bf16(wa, af[s], acc, 0, 0, 0);
            }
            acc1[t] = acc;
        }

        // pack: pb[s2] = bf16x8 of silu(acc1 + b2) per the k_hw->n permutation
        bf16x8 pb[4];
#pragma unroll
        for (int s2 = 0; s2 < 4; s2++) {
#pragma unroll
            for (int half = 0; half < 2; half++) {
                int t = 2 * s2 + half;
                float4 b2q = *(const float4*)&s_b2[t * 16 + 4 * g];
#pragma unroll
                for (int jj = 0; jj < 4; jj++) {
                    float bq = (jj == 0) ? b2q.x : (jj == 1) ? b2q.y
                             : (jj == 2) ? b2q.z : b2q.w;
                    pb[s2][half * 4 + jj] = (bf16)fast_silu(acc1[t][jj] + bq);
                }
            }
        }

        // GEMM2 swapped + fused silu*W4 partial reduction
        float part = 0.f;
#pragma unroll
        for (int t2 = 0; t2 < 8; t2++) {
            f32x4 acc = {0.f, 0.f, 0.f, 0.f};
#pragma unroll
            for (int s2 = 0; s2 < 4; s2++) {
                bf16x8 wa = *(const bf16x8*)(w3base + (s2 * 8 + t2) * 512);
                acc = __builtin_amdgcn_mfma_f32_16x16x32_bf16(wa, pb[s2], acc, 0, 0, 0);
            }
            // rows n2 = t2*16 + 4g + jj ; (b3,W4) pairs
            float4 p0 = *(const float4*)&s_bw[2 * (t2 * 16 + 4 * g)];
            float4 p1 = *(const float4*)&s_bw[2 * (t2 * 16 + 4 * g) + 4];
            part += fast_silu(acc[0] + p0.x) * p0.y;
            part += fast_silu(acc[1] + p0.z) * p0.w;
            part += fast_silu(acc[2] + p1.x) * p1.y;
            part += fast_silu(acc[3] + p1.z) * p1.w;
        }
        // reduce over the 4 lane-groups: lanes sharing r -> full scale of edge r
        part += __shfl_xor(part, 16);
        part += __shfl_xor(part, 32);
        float scale_r = part + b4v;

        // scatter: lane = m*4 + c
        {
            int m = lane >> 2, c3 = lane & 3;
            float sc = __shfl(scale_r, m);     // lane m holds edge m's scale
            int eim = __shfl(ei, m);
            if (c3 < 3)
                atomicAdd(&out[(size_t)eim * 3 + c3],
                          dxv[(size_t)(base + m) * 3 + c3] * sc);
        }
    }
}

extern "C" void kernel_launch(void* const* d_in, const int* in_sizes, int n_in,
                              void* d_out, int out_size, void* d_ws, size_t ws_size,
                              hipStream_t stream) {
    const float* h   = (const float*)d_in[0];
    const float* x   = (const float*)d_in[1];
    const int*   e   = (const int*)d_in[2];
    const float* dxv = (const float*)d_in[3];
    const float* d2  = (const float*)d_in[4];
    const float* W1  = (const float*)d_in[5];
    const float* b1  = (const float*)d_in[6];
    const float* g1  = (const float*)d_in[7];
    const float* bt1 = (const float*)d_in[8];
    const float* W2  = (const float*)d_in[9];
    const float* b2  = (const float*)d_in[10];
    const float* W3  = (const float*)d_in[11];
    const float* b3  = (const float*)d_in[12];
    const float* W4  = (const float*)d_in[13];
    const float* b4  = (const float*)d_in[14];

    char* ws = (char*)d_ws;
    bf16* An     = (bf16*)(ws);                        // 12,800,000
    bf16* Bn     = (bf16*)(ws + 12800000);             // 12,800,000
    bf16* w1aT   = (bf16*)(ws + 25600000);             // 32768
    bf16* w1bT   = (bf16*)(ws + 25632768);             // 32768
    bf16* w2T    = (bf16*)(ws + 25665536);             // 32768
    bf16* w3P    = (bf16*)(ws + 25698304);             // 32768
    float* smalls = (float*)(ws + 25731072);           // 4608
    float* out   = (float*)d_out;

    prep_kernel<<<64, 256, 0, stream>>>(W1, W2, W3, b1, g1, bt1, b2, b3, W4,
                                        w1aT, w1bT, w2T, w3P, smalls);
    node_kernel<<<(NN / 16 + 3) / 4, 256, 0, stream>>>(h, w1aT, w1bT, An, Bn);
    init_kernel<<<(NN * 3 + 255) / 256, 256, 0, stream>>>(x, out, NN * 3);
    edge_kernel<<<512, 512, 0, stream>>>(An, Bn, w2T, w3P, smalls, b4,
                                         e, dxv, d2, out);
}